// Round 6
// baseline (293.120 us; speedup 1.0000x reference)
//
#include <hip/hip_runtime.h>
#include <cstdint>
#include <cstddef>

// Problem constants (match reference setup_inputs)
#define BB 32
#define SS 4096          // 2^12
#define FEAT_ 64
#define HID_ 32
#define NN 1024          // MAX_NODES
#define RPB 8            // adjacency rows per block (dense LDS tile = 32 KB)

typedef float v4f __attribute__((ext_vector_type(4)));

// ---------------------------------------------------------------------------
// Kernel 0: high-BW zero fill of the adjacency region. Grid-stride, 16 nt
// float4 stores per thread — fill-kernel shape, so stores stay deeply
// pipelined (adj_dense's 8 end-of-life stores were latency-bound at 2 TB/s;
// the rocclr fill demonstrates 6.7 TB/s is available).
// ---------------------------------------------------------------------------
__global__ void zero_adj_kernel(v4f* __restrict__ adj4, int n4) {
    int i = blockIdx.x * blockDim.x + threadIdx.x;
    int stride = gridDim.x * blockDim.x;
    v4f z = {0.f, 0.f, 0.f, 0.f};
    for (; i < n4; i += stride)
        __builtin_nontemporal_store(z, &adj4[i]);
}

// ---------------------------------------------------------------------------
// Kernel 1: node_features via GATHER (no atomics) + fused L2-normalize.
// Block = 256 threads = 4 waves; block owns 16 rows (4 per wave) of one
// batch. Row sums accumulate in-register in s-order (deterministic),
// butterfly L2-normalize, non-temporal row writes.
// ---------------------------------------------------------------------------
__global__ void node_feat_kernel(const float* __restrict__ flow,
                                 const int* __restrict__ dst,
                                 float* __restrict__ nf) {
    int row0 = blockIdx.x << 4;              // global row = b*NN + node
    int b = row0 >> 10;
    __shared__ int sdst[SS];

    const int4* g = (const int4*)(dst + (size_t)b * SS);
    int4* sd4 = (int4*)sdst;
    for (int i = threadIdx.x; i < SS / 4; i += 256) sd4[i] = g[i];
    __syncthreads();

    int wave = threadIdx.x >> 6;
    int lane = threadIdx.x & 63;
    int r0 = row0 + (wave << 2);             // this wave's first row
    int node0 = r0 & (NN - 1);
    const float* fb = flow + ((size_t)b * SS << 6);

    float acc[4] = {0.f, 0.f, 0.f, 0.f};
    for (int s0 = 0; s0 < SS; s0 += 64) {
        int d = sdst[s0 + lane];
        #pragma unroll
        for (int j = 0; j < 4; ++j) {
            unsigned long long m = __ballot(d == node0 + j);
            while (m) {                      // ~1 hit/wave/j over whole scan
                int bit = __ffsll((long long)m) - 1;
                m &= m - 1;
                acc[j] += fb[((s0 + bit) << 6) + lane];  // coalesced 256 B row
            }
        }
    }

    #pragma unroll
    for (int j = 0; j < 4; ++j) {
        float ss = acc[j] * acc[j];
        #pragma unroll
        for (int off = 32; off > 0; off >>= 1) ss += __shfl_xor(ss, off, 64);
        float v = acc[j] / fmaxf(sqrtf(ss), 1e-12f);
        __builtin_nontemporal_store(v, &nf[((size_t)(r0 + j) << 6) + lane]);
    }
}

// ---------------------------------------------------------------------------
// Kernel 2: edge MLP -> weight w[b,s] into workspace. No adjacency access.
// ---------------------------------------------------------------------------
__global__ void mlp_kernel(const int* __restrict__ src,
                           const int* __restrict__ dst,
                           const float* __restrict__ vol,
                           const float* __restrict__ emb,
                           const float* __restrict__ W1,
                           const float* __restrict__ b1,
                           const float* __restrict__ W2,
                           const float* __restrict__ b2,
                           float* __restrict__ wout) {
    int i = blockIdx.x * blockDim.x + threadIdx.x;  // b*S + s
    int si = src[i], di = dst[i];

    float acc[HID_];
    #pragma unroll
    for (int j = 0; j < HID_; ++j) acc[j] = b1[j];

    // h = relu([emb[src]; emb[dst]] @ W1 + b1). W1 accesses are wave-uniform
    // (scalar-load friendly); emb rows are gathered, 256 B each, L2-resident.
    #pragma unroll
    for (int half = 0; half < 2; ++half) {
        const float* e = emb + ((half ? di : si) << 6);
        const float* w = W1 + half * 64 * HID_;
        for (int k = 0; k < 64; k += 4) {
            float4 v = *(const float4*)(e + k);
            #pragma unroll
            for (int j = 0; j < HID_; ++j) {
                float a = acc[j];
                a += v.x * w[(k + 0) * HID_ + j];
                a += v.y * w[(k + 1) * HID_ + j];
                a += v.z * w[(k + 2) * HID_ + j];
                a += v.w * w[(k + 3) * HID_ + j];
                acc[j] = a;
            }
        }
    }

    float dotv = b2[0];
    #pragma unroll
    for (int j = 0; j < HID_; ++j) dotv += fmaxf(acc[j], 0.0f) * W2[j];
    float edge_w = 1.0f / (1.0f + expf(-dotv));
    float vol_w  = 1.0f / (1.0f + expf(-vol[i] / 1000.0f));
    wout[i] = edge_w * vol_w;
}

// ---------------------------------------------------------------------------
// Kernel 3: sparse adjacency resolve+scatter. Block owns RPB=8 rows of one
// batch: D[8][1024] ints (32 KB dense LDS priority tile).
//   phase 0: zero D
//   phase 1: matched edges atomicMax prio into D
//            prio = s+1 (pass-1 cell src,dst) / S+s+1 (pass-2 cell dst,src)
//            ranges disjoint & unique -> max == numpy last-write-wins
//   phase 2: the unique max-prio winner per cell replaces prio with w bits
//            (w in (0,1) has bit pattern >> 8192, never equals a prio)
//   phase 3: every matched edge re-reads its cell (now holding the winner's
//            w bits) and scatters it to global adj — losers write the same
//            resolved value as the winner (benign duplicate store). Only
//            ~64 scattered dword stores per block; the 134 MB zero
//            background comes from zero_adj_kernel at fill bandwidth.
// ---------------------------------------------------------------------------
__global__ void adj_sparse_kernel(const int* __restrict__ src,
                                  const int* __restrict__ dst,
                                  const float* __restrict__ wbuf,
                                  int* __restrict__ adj) {
    int b  = blockIdx.x >> 7;                 // 128 blocks per batch
    int r0 = (blockIdx.x & 127) << 3;         // first of RPB rows
    int tid = threadIdx.x;

    __shared__ int D[RPB * NN];               // 32 KB dense tile

    // register-cache this thread's 16 edge (src,dst) pairs while zeroing D
    const int* sb = src + (size_t)b * SS;
    const int* db = dst + (size_t)b * SS;
    int svr[16], dvr[16];
    #pragma unroll
    for (int i = 0; i < 16; ++i) {
        svr[i] = sb[tid + (i << 8)];
        dvr[i] = db[tid + (i << 8)];
    }

    int4* D4 = (int4*)D;
    int4 z; z.x = z.y = z.z = z.w = 0;
    #pragma unroll
    for (int i = 0; i < RPB * NN / 4 / 256; ++i) D4[tid + i * 256] = z;
    __syncthreads();

    // phase 1: priority max
    #pragma unroll
    for (int i = 0; i < 16; ++i) {
        int s = tid + (i << 8);
        unsigned lr1 = (unsigned)(svr[i] - r0);
        if (lr1 < RPB) atomicMax(&D[(lr1 << 10) + dvr[i]], s + 1);
        unsigned lr2 = (unsigned)(dvr[i] - r0);
        if (lr2 < RPB) atomicMax(&D[(lr2 << 10) + svr[i]], SS + s + 1);
    }
    __syncthreads();

    // phase 2: winners deposit w bits
    const float* wb = wbuf + (size_t)b * SS;
    #pragma unroll
    for (int i = 0; i < 16; ++i) {
        int s = tid + (i << 8);
        unsigned lr1 = (unsigned)(svr[i] - r0);
        unsigned lr2 = (unsigned)(dvr[i] - r0);
        if ((lr1 < RPB) | (lr2 < RPB)) {
            int wbits = __float_as_int(wb[s]);
            if (lr1 < RPB && D[(lr1 << 10) + dvr[i]] == s + 1)
                D[(lr1 << 10) + dvr[i]] = wbits;
            if (lr2 < RPB && D[(lr2 << 10) + svr[i]] == SS + s + 1)
                D[(lr2 << 10) + svr[i]] = wbits;
        }
    }
    __syncthreads();

    // phase 3: scatter resolved cells to global (duplicates store same value)
    int* ab = adj + (size_t)b * NN * NN;
    #pragma unroll
    for (int i = 0; i < 16; ++i) {
        unsigned lr1 = (unsigned)(svr[i] - r0);
        if (lr1 < RPB)
            ab[(size_t)(r0 + lr1) * NN + dvr[i]] = D[(lr1 << 10) + dvr[i]];
        unsigned lr2 = (unsigned)(dvr[i] - r0);
        if (lr2 < RPB)
            ab[(size_t)(r0 + lr2) * NN + svr[i]] = D[(lr2 << 10) + svr[i]];
    }
}

extern "C" void kernel_launch(void* const* d_in, const int* in_sizes, int n_in,
                              void* d_out, int out_size, void* d_ws, size_t ws_size,
                              hipStream_t stream) {
    const float* flow = (const float*)d_in[0];   // (B,S,64)
    const int*   src  = (const int*)d_in[1];     // (B,S)
    const int*   dst  = (const int*)d_in[2];     // (B,S)
    const float* vol  = (const float*)d_in[3];   // (B,S)
    const float* emb  = (const float*)d_in[4];   // (1024,64)
    const float* W1   = (const float*)d_in[5];   // (128,32)
    const float* b1   = (const float*)d_in[6];   // (32,)
    const float* W2   = (const float*)d_in[7];   // (32,1)
    const float* b2   = (const float*)d_in[8];   // (1,)

    float* nf  = (float*)d_out;                         // (B,N,64)
    float* adj = nf + (size_t)BB * NN * FEAT_;          // (B,N,N)
    float* wbuf = (float*)d_ws;                         // (B,S) edge weights

    const int adj_f4 = BB * NN * NN / 4;                // 8,388,608 float4s

    // Streaming zero of adj first (saturates write BW); nf needs no zeroing.
    zero_adj_kernel<<<2048, 256, 0, stream>>>((v4f*)adj, adj_f4);
    mlp_kernel<<<(BB * SS) / 256, 256, 0, stream>>>(src, dst, vol, emb,
                                                    W1, b1, W2, b2, wbuf);
    adj_sparse_kernel<<<BB * (NN / RPB), 256, 0, stream>>>(src, dst, wbuf,
                                                           (int*)adj);
    node_feat_kernel<<<(BB * NN) / 16, 256, 0, stream>>>(flow, dst, nf);
}

// Round 7
// 242.927 us; speedup vs baseline: 1.2066x; 1.2066x over previous
//
#include <hip/hip_runtime.h>
#include <cstdint>
#include <cstddef>

// Problem constants (match reference setup_inputs)
#define BB 32
#define SS 4096          // 2^12
#define FEAT_ 64
#define HID_ 32
#define NN 1024          // MAX_NODES
#define RPB 8            // adjacency rows per block (dense LDS tile = 32 KB)

typedef int v4i __attribute__((ext_vector_type(4)));

// ---------------------------------------------------------------------------
// Kernel 1: node_features via GATHER (no atomics) + fused L2-normalize.
// Block = 256 threads = 4 waves; block owns 16 rows (4 per wave) of one
// batch. Row sums accumulate in-register in s-order (deterministic),
// butterfly L2-normalize, non-temporal row writes.
// ---------------------------------------------------------------------------
__global__ void node_feat_kernel(const float* __restrict__ flow,
                                 const int* __restrict__ dst,
                                 float* __restrict__ nf) {
    int row0 = blockIdx.x << 4;              // global row = b*NN + node
    int b = row0 >> 10;
    __shared__ int sdst[SS];

    const int4* g = (const int4*)(dst + (size_t)b * SS);
    int4* sd4 = (int4*)sdst;
    for (int i = threadIdx.x; i < SS / 4; i += 256) sd4[i] = g[i];
    __syncthreads();

    int wave = threadIdx.x >> 6;
    int lane = threadIdx.x & 63;
    int r0 = row0 + (wave << 2);             // this wave's first row
    int node0 = r0 & (NN - 1);
    const float* fb = flow + ((size_t)b * SS << 6);

    float acc[4] = {0.f, 0.f, 0.f, 0.f};
    for (int s0 = 0; s0 < SS; s0 += 64) {
        int d = sdst[s0 + lane];
        #pragma unroll
        for (int j = 0; j < 4; ++j) {
            unsigned long long m = __ballot(d == node0 + j);
            while (m) {                      // ~1 hit/wave/j over whole scan
                int bit = __ffsll((long long)m) - 1;
                m &= m - 1;
                acc[j] += fb[((s0 + bit) << 6) + lane];  // coalesced 256 B row
            }
        }
    }

    #pragma unroll
    for (int j = 0; j < 4; ++j) {
        float ss = acc[j] * acc[j];
        #pragma unroll
        for (int off = 32; off > 0; off >>= 1) ss += __shfl_xor(ss, off, 64);
        float v = acc[j] / fmaxf(sqrtf(ss), 1e-12f);
        __builtin_nontemporal_store(v, &nf[((size_t)(r0 + j) << 6) + lane]);
    }
}

// ---------------------------------------------------------------------------
// Kernel 2: edge MLP -> weight w[b,s] into workspace. No adjacency access.
// ---------------------------------------------------------------------------
__global__ void mlp_kernel(const int* __restrict__ src,
                           const int* __restrict__ dst,
                           const float* __restrict__ vol,
                           const float* __restrict__ emb,
                           const float* __restrict__ W1,
                           const float* __restrict__ b1,
                           const float* __restrict__ W2,
                           const float* __restrict__ b2,
                           float* __restrict__ wout) {
    int i = blockIdx.x * blockDim.x + threadIdx.x;  // b*S + s
    int si = src[i], di = dst[i];

    float acc[HID_];
    #pragma unroll
    for (int j = 0; j < HID_; ++j) acc[j] = b1[j];

    // h = relu([emb[src]; emb[dst]] @ W1 + b1). W1 accesses are wave-uniform
    // (scalar-load friendly); emb rows are gathered, 256 B each, L2-resident.
    #pragma unroll
    for (int half = 0; half < 2; ++half) {
        const float* e = emb + ((half ? di : si) << 6);
        const float* w = W1 + half * 64 * HID_;
        for (int k = 0; k < 64; k += 4) {
            float4 v = *(const float4*)(e + k);
            #pragma unroll
            for (int j = 0; j < HID_; ++j) {
                float a = acc[j];
                a += v.x * w[(k + 0) * HID_ + j];
                a += v.y * w[(k + 1) * HID_ + j];
                a += v.z * w[(k + 2) * HID_ + j];
                a += v.w * w[(k + 3) * HID_ + j];
                acc[j] = a;
            }
        }
    }

    float dotv = b2[0];
    #pragma unroll
    for (int j = 0; j < HID_; ++j) dotv += fmaxf(acc[j], 0.0f) * W2[j];
    float edge_w = 1.0f / (1.0f + expf(-dotv));
    float vol_w  = 1.0f / (1.0f + expf(-vol[i] / 1000.0f));
    wout[i] = edge_w * vol_w;
}

// ---------------------------------------------------------------------------
// Kernel 3: adjacency via dense LDS priority tile. Block owns RPB=8 rows of
// one batch: D[8][1024] ints (32 KB). Single write pass over the adjacency
// (measured pure-write ceiling ~2 TB/s: any second pass over the 134 MB is
// a net loss — round 6 proved this).
//   phase 0: zero D (untouched cells -> 0.0f for free)
//   phase 1: matched edges atomicMax prio into D
//            prio = s+1 (pass-1 cell src,dst) / S+s+1 (pass-2 cell dst,src)
//            ranges disjoint & unique -> max == numpy last-write-wins
//   phase 2: the unique max-prio winner per cell replaces prio with w bits
//   phase 3: prefetch all 8 LDS lines to registers, then 8 back-to-back
//            NON-TEMPORAL float4 stores (no interleaved lgkm waits, max
//            stores in flight; nt bypasses L2 write-allocate thrash).
// src/dst values are register-cached across phases (16 pairs/thread), so
// global edge reads happen exactly once per block.
// ---------------------------------------------------------------------------
__global__ void adj_dense_kernel(const int* __restrict__ src,
                                 const int* __restrict__ dst,
                                 const float* __restrict__ wbuf,
                                 float* __restrict__ adj) {
    int b  = blockIdx.x >> 7;                 // 128 blocks per batch
    int r0 = (blockIdx.x & 127) << 3;         // first of RPB rows
    int tid = threadIdx.x;

    __shared__ int D[RPB * NN];               // 32 KB dense tile

    // register-cache this thread's 16 edge (src,dst) pairs while zeroing D
    const int* sb = src + (size_t)b * SS;
    const int* db = dst + (size_t)b * SS;
    int svr[16], dvr[16];
    #pragma unroll
    for (int i = 0; i < 16; ++i) {
        svr[i] = sb[tid + (i << 8)];
        dvr[i] = db[tid + (i << 8)];
    }

    int4* D4 = (int4*)D;
    int4 z; z.x = z.y = z.z = z.w = 0;
    #pragma unroll
    for (int i = 0; i < RPB * NN / 4 / 256; ++i) D4[tid + i * 256] = z;
    __syncthreads();

    // phase 1: priority max
    #pragma unroll
    for (int i = 0; i < 16; ++i) {
        int s = tid + (i << 8);
        unsigned lr1 = (unsigned)(svr[i] - r0);
        if (lr1 < RPB) atomicMax(&D[(lr1 << 10) + dvr[i]], s + 1);
        unsigned lr2 = (unsigned)(dvr[i] - r0);
        if (lr2 < RPB) atomicMax(&D[(lr2 << 10) + svr[i]], SS + s + 1);
    }
    __syncthreads();

    // phase 2: winners deposit w bits
    const float* wb = wbuf + (size_t)b * SS;
    #pragma unroll
    for (int i = 0; i < 16; ++i) {
        int s = tid + (i << 8);
        unsigned lr1 = (unsigned)(svr[i] - r0);
        unsigned lr2 = (unsigned)(dvr[i] - r0);
        if ((lr1 < RPB) | (lr2 < RPB)) {
            int wbits = __float_as_int(wb[s]);
            if (lr1 < RPB && D[(lr1 << 10) + dvr[i]] == s + 1)
                D[(lr1 << 10) + dvr[i]] = wbits;
            if (lr2 < RPB && D[(lr2 << 10) + svr[i]] == SS + s + 1)
                D[(lr2 << 10) + svr[i]] = wbits;
        }
    }
    __syncthreads();

    // phase 3: prefetch LDS -> regs, then back-to-back nt stores
    const v4i* Df = (const v4i*)D;
    v4i* out = (v4i*)(adj + ((size_t)b * NN + r0) * NN);
    v4i r[RPB * NN / 4 / 256];
    #pragma unroll
    for (int i = 0; i < RPB * NN / 4 / 256; ++i) r[i] = Df[tid + i * 256];
    #pragma unroll
    for (int i = 0; i < RPB * NN / 4 / 256; ++i)
        __builtin_nontemporal_store(r[i], &out[tid + i * 256]);
}

extern "C" void kernel_launch(void* const* d_in, const int* in_sizes, int n_in,
                              void* d_out, int out_size, void* d_ws, size_t ws_size,
                              hipStream_t stream) {
    const float* flow = (const float*)d_in[0];   // (B,S,64)
    const int*   src  = (const int*)d_in[1];     // (B,S)
    const int*   dst  = (const int*)d_in[2];     // (B,S)
    const float* vol  = (const float*)d_in[3];   // (B,S)
    const float* emb  = (const float*)d_in[4];   // (1024,64)
    const float* W1   = (const float*)d_in[5];   // (128,32)
    const float* b1   = (const float*)d_in[6];   // (32,)
    const float* W2   = (const float*)d_in[7];   // (32,1)
    const float* b2   = (const float*)d_in[8];   // (1,)

    float* nf  = (float*)d_out;                         // (B,N,64)
    float* adj = nf + (size_t)BB * NN * FEAT_;          // (B,N,N)
    float* wbuf = (float*)d_ws;                         // (B,S) edge weights

    // Every output byte is written exactly once by the kernels below —
    // no memset of d_out at all.
    mlp_kernel<<<(BB * SS) / 256, 256, 0, stream>>>(src, dst, vol, emb,
                                                    W1, b1, W2, b2, wbuf);
    adj_dense_kernel<<<BB * (NN / RPB), 256, 0, stream>>>(src, dst, wbuf, adj);
    node_feat_kernel<<<(BB * NN) / 16, 256, 0, stream>>>(flow, dst, nf);
}